// Round 1
// 106.372 us; speedup vs baseline: 1.0291x; 1.0291x over previous
//
#include <hip/hip_runtime.h>
#include <math.h>

#define DEG 32
#define NHO 64   // HEADS*OUT_F = 4*16
#define NPW 4    // nodes per wave in gat_kernel
#define NPB 16   // nodes per block (4 waves * NPW)

typedef short  frag8  __attribute__((ext_vector_type(8)));   // 8 bf16 = 4 VGPRs
typedef float  f32x4  __attribute__((ext_vector_type(4)));

// DPP butterfly add within quads (4 lanes): xor1 = quad_perm[1,0,3,2]=0xB1,
// xor2 = quad_perm[2,3,0,1]=0x4E.
template <int CTRL>
__device__ __forceinline__ float dpp_add(float v) {
    int t = __builtin_amdgcn_update_dpp(0, __float_as_int(v), CTRL, 0xF, 0xF, true);
    return v + __int_as_float(t);
}

__device__ __forceinline__ unsigned bf16_rne(float f) {
    unsigned u = __float_as_uint(f);
    return (u + 0x7fffu + ((u >> 16) & 1u)) >> 16;
}

// ---------------------------------------------------------------------------
// MFMA projection: C[128][N] = W'[128][64] x Q[64][N]; rows 0-63 -> Pqb,
// rows 64-127 -> Pkb, both bf16 [N][64] (128 B rows).  (unchanged this round)
// ---------------------------------------------------------------------------
__global__ __launch_bounds__(256) void proj_mfma_kernel(
    const float* __restrict__ Q,
    const float* __restrict__ Wq,
    const float* __restrict__ Wk,
    unsigned short* __restrict__ Pqb,
    unsigned short* __restrict__ Pkb,
    int N)
{
    __shared__ unsigned qlds[64 * 33];    // [n][k-pair]
    __shared__ unsigned wlds[128 * 33];   // [l][k-pair]

    int t  = threadIdx.x;
    int n0 = blockIdx.x * 64;

    {
        int l    = t >> 1;
        int half = t & 1;
        const float* wr = (l < 64 ? Wq + (size_t)l * 64
                                  : Wk + (size_t)(l - 64) * 64) + half * 32;
#pragma unroll
        for (int r = 0; r < 16; r++) {
            float f0 = wr[2 * r], f1 = wr[2 * r + 1];
            wlds[l * 33 + half * 16 + r] = bf16_rne(f0) | (bf16_rne(f1) << 16);
        }
    }
    {
        int n  = t & 63;
        int gn = n0 + n;
        bool act = (gn < N);
#pragma unroll
        for (int r = 0; r < 8; r++) {
            int dp = (t >> 6) * 8 + r;
            int k  = dp * 2;
            float f0 = act ? Q[(size_t)k * N + gn] : 0.f;
            float f1 = act ? Q[(size_t)(k + 1) * N + gn] : 0.f;
            qlds[n * 33 + dp] = bf16_rne(f0) | (bf16_rne(f1) << 16);
        }
    }
    __syncthreads();

    int lane = t & 63;
    int w    = t >> 6;
    int li   = lane & 15;
    int quad = lane >> 4;

    f32x4 acc[8];
#pragma unroll
    for (int ot = 0; ot < 8; ot++) acc[ot] = (f32x4){0.f, 0.f, 0.f, 0.f};

#pragma unroll
    for (int ks = 0; ks < 2; ks++) {
        union { unsigned u[4]; frag8 f; } A;
        int abase = (w * 16 + li) * 33 + ks * 16 + quad * 4;
#pragma unroll
        for (int c = 0; c < 4; c++) A.u[c] = qlds[abase + c];
#pragma unroll
        for (int ot = 0; ot < 8; ot++) {
            union { unsigned u[4]; frag8 f; } B;
            int bbase = (ot * 16 + li) * 33 + ks * 16 + quad * 4;
#pragma unroll
            for (int c = 0; c < 4; c++) B.u[c] = wlds[bbase + c];
            acc[ot] = __builtin_amdgcn_mfma_f32_16x16x32_bf16(A.f, B.f, acc[ot],
                                                              0, 0, 0);
        }
    }

#pragma unroll
    for (int ot = 0; ot < 8; ot++) {
#pragma unroll
        for (int r = 0; r < 4; r++) {
            int node = n0 + w * 16 + quad * 4 + r;
            if (node < N) {
                unsigned short v = (unsigned short)bf16_rne(acc[ot][r]);
                if (ot < 4)
                    Pqb[(size_t)node * NHO + ot * 16 + li] = v;
                else
                    Pkb[(size_t)node * NHO + (ot - 4) * 16 + li] = v;
            }
        }
    }
}

// ---------------------------------------------------------------------------
// GAT helpers
// ---------------------------------------------------------------------------

// xor16 within each 32-lane half, via ds_swizzle bitmode: xor=16,and=0x1F.
// Bit-identical lane pairing to ds_bpermute((l^16)*4, v).
__device__ __forceinline__ float swz_x16(float v) {
    return __int_as_float(__builtin_amdgcn_ds_swizzle(__float_as_int(v), 0x401F));
}
__device__ __forceinline__ float bprm(int addr, float v) {
    return __int_as_float(__builtin_amdgcn_ds_bpermute(addr, __float_as_int(v)));
}

// Issue the 8 neighbor-row gathers for one node (slot s covers edges
// s*8 .. s*8+7; lo/hi hold those 8 edge ids, identical across the 16 lanes
// of a slot). dst is consumed later -> loads stay in flight (counted vmcnt).
__device__ __forceinline__ void gat_gather(uint2 (&dst)[8],
                                           const int4 lo, const int4 hi,
                                           const uint2* __restrict__ Pk64,
                                           int sl) {
    dst[0] = Pk64[(size_t)(lo.x < 0 ? 0 : lo.x) * 16 + sl];
    dst[1] = Pk64[(size_t)(lo.y < 0 ? 0 : lo.y) * 16 + sl];
    dst[2] = Pk64[(size_t)(lo.z < 0 ? 0 : lo.z) * 16 + sl];
    dst[3] = Pk64[(size_t)(lo.w < 0 ? 0 : lo.w) * 16 + sl];
    dst[4] = Pk64[(size_t)(hi.x < 0 ? 0 : hi.x) * 16 + sl];
    dst[5] = Pk64[(size_t)(hi.y < 0 ? 0 : hi.y) * 16 + sl];
    dst[6] = Pk64[(size_t)(hi.z < 0 ? 0 : hi.z) * 16 + sl];
    dst[7] = Pk64[(size_t)(hi.w < 0 ? 0 : hi.w) * 16 + sl];
}

// Full per-node compute: t-loop (8 edges/slot), cross-slot butterfly,
// normalized tile write. Math order identical to the verified kernel.
__device__ __forceinline__ void gat_compute(
    const uint2 (&kv)[8], const int4 lo, const int4 hi, uint2 qraw,
    float c1_0, float c1_1, float c1_2, float c1_3,
    float c2_0, float c2_1, float c2_2, float c2_3,
    int slot, int sl, int bprm_x32, int col,
    float (&tile)[NHO][NPB + 1])
{
    float qp0 = __uint_as_float(qraw.x << 16);
    float qp1 = __uint_as_float(qraw.x & 0xffff0000u);
    float qp2 = __uint_as_float(qraw.y << 16);
    float qp3 = __uint_as_float(qraw.y & 0xffff0000u);

    float c1q = c1_0 * qp0;
    c1q = fmaf(c1_1, qp1, c1q);
    c1q = fmaf(c1_2, qp2, c1q);
    c1q = fmaf(c1_3, qp3, c1q);

    const int jt[8] = {lo.x, lo.y, lo.z, lo.w, hi.x, hi.y, hi.z, hi.w};

    float s = 0.f, a0 = 0.f, a1 = 0.f, a2 = 0.f, a3 = 0.f;
#pragma unroll
    for (int t = 0; t < 8; t++) {
        float kv0 = __uint_as_float(kv[t].x << 16);
        float kv1 = __uint_as_float(kv[t].x & 0xffff0000u);
        float kv2 = __uint_as_float(kv[t].y << 16);
        float kv3 = __uint_as_float(kv[t].y & 0xffff0000u);
        float x0 = qp0 + kv0, x1 = qp1 + kv1;
        float x2 = qp2 + kv2, x3 = qp3 + kv3;
        float c = fmaf(c1_0, kv0, c1q);
        c = fmaf(c1_1, kv1, c);
        c = fmaf(c1_2, kv2, c);
        c = fmaf(c1_3, kv3, c);
        c = fmaf(c2_0, fabsf(x0), c);
        c = fmaf(c2_1, fabsf(x1), c);
        c = fmaf(c2_2, fabsf(x2), c);
        c = fmaf(c2_3, fabsf(x3), c);
        c = dpp_add<0xB1>(c);     // xor 1 (within quad)
        c = dpp_add<0x4E>(c);     // xor 2 (within quad)
        float p = __builtin_amdgcn_exp2f(c);
        p = (jt[t] >= 0) ? p : 0.f;
        s += p;
        a0 = fmaf(p, kv0, a0);
        a1 = fmaf(p, kv1, a1);
        a2 = fmaf(p, kv2, a2);
        a3 = fmaf(p, kv3, a3);
    }

    // butterfly-combine the 4 edge slots (xor16 via ds_swizzle, xor32 via bpermute)
    s  += swz_x16(s);
    a0 += swz_x16(a0);
    a1 += swz_x16(a1);
    a2 += swz_x16(a2);
    a3 += swz_x16(a3);
    s  += bprm(bprm_x32, s);
    a0 += bprm(bprm_x32, a0);
    a1 += bprm(bprm_x32, a1);
    a2 += bprm(bprm_x32, a2);
    a3 += bprm(bprm_x32, a3);

    float rs = (s > 0.f) ? __builtin_amdgcn_rcpf(s) : 0.f;
    if (slot == 0) {
        tile[4 * sl + 0][col] = a0 * rs;
        tile[4 * sl + 1][col] = a1 * rs;
        tile[4 * sl + 2][col] = a2 * rs;
        tile[4 * sl + 3][col] = a3 * rs;
    }
}

// ---------------------------------------------------------------------------
// GAT kernel, pipelined: adj/Pq rows for all NPW nodes prefetched up front
// (direct broadcast int4 loads replace the ds_bpermute distribution), then a
// double-buffered gather pipeline: node ni+1's 8 gathers are issued BEFORE
// node ni's compute, so gather latency hides under a full compute phase.
// __launch_bounds__(256,4): cap VGPRs at 128 -> keep 4 waves/SIMD.
// ---------------------------------------------------------------------------
__global__ __launch_bounds__(256, 4) void gat_kernel(
    const int*            __restrict__ adj,   // [N][DEG]
    const unsigned short* __restrict__ Pqb,   // [N][64] bf16
    const unsigned short* __restrict__ Pkb,   // [N][64] bf16
    const float*          __restrict__ aw,    // [64]
    float*                __restrict__ out,   // [64][N]
    int N)
{
    __shared__ float tile[NHO][NPB + 1];

    int l    = threadIdx.x & 63;
    int wv   = threadIdx.x >> 6;
    int sl   = l & 15;
    int slot = l >> 4;

    const uint2* Pk64 = (const uint2*)Pkb;   // 16 uint2 per row
    const uint2* Pq64 = (const uint2*)Pqb;

    float4 awq = *(const float4*)(aw + 4 * sl);
    const float L2E = 1.44269504f;
    float c1_0 = 0.505f * L2E * awq.x, c2_0 = 0.495f * L2E * awq.x;
    float c1_1 = 0.505f * L2E * awq.y, c2_1 = 0.495f * L2E * awq.y;
    float c1_2 = 0.505f * L2E * awq.z, c2_2 = 0.495f * L2E * awq.z;
    float c1_3 = 0.505f * L2E * awq.w, c2_3 = 0.495f * L2E * awq.w;

    int bprm_x32 = (l ^ 32) * 4;
    int nbase = blockIdx.x * NPB + wv * NPW;

    if (nbase + NPW <= N) {
        // ---- fast path (always taken at N=50000: 3125*16 == 50000) ----
        int4  aLo[NPW], aHi[NPW];
        uint2 qr[NPW];
#pragma unroll
        for (int ni = 0; ni < NPW; ni++) {
            const int* ap = adj + (size_t)(nbase + ni) * DEG + slot * 8;
            aLo[ni] = *(const int4*)ap;         // edges slot*8 .. +3 (broadcast)
            aHi[ni] = *(const int4*)(ap + 4);   // edges slot*8+4 .. +7
            qr[ni]  = Pq64[(size_t)(nbase + ni) * 16 + sl];
        }

        uint2 kvA[8], kvB[8];
        gat_gather(kvA, aLo[0], aHi[0], Pk64, sl);   // prologue: node 0

#pragma unroll
        for (int ni = 0; ni < NPW; ni++) {
            int col = wv * NPW + ni;
            if ((ni & 1) == 0) {
                if (ni + 1 < NPW)
                    gat_gather(kvB, aLo[ni + 1], aHi[ni + 1], Pk64, sl);
                gat_compute(kvA, aLo[ni], aHi[ni], qr[ni],
                            c1_0, c1_1, c1_2, c1_3, c2_0, c2_1, c2_2, c2_3,
                            slot, sl, bprm_x32, col, tile);
            } else {
                if (ni + 1 < NPW)
                    gat_gather(kvA, aLo[ni + 1], aHi[ni + 1], Pk64, sl);
                gat_compute(kvB, aLo[ni], aHi[ni], qr[ni],
                            c1_0, c1_1, c1_2, c1_3, c2_0, c2_1, c2_2, c2_3,
                            slot, sl, bprm_x32, col, tile);
            }
        }
    } else {
        // ---- guarded tail path (generic N) ----
        uint2 kvA[8];
#pragma unroll 1
        for (int ni = 0; ni < NPW; ni++) {
            int n = nbase + ni;
            if (n < N) {
                const int* ap = adj + (size_t)n * DEG + slot * 8;
                int4 lo = *(const int4*)ap;
                int4 hi = *(const int4*)(ap + 4);
                uint2 qraw = Pq64[(size_t)n * 16 + sl];
                gat_gather(kvA, lo, hi, Pk64, sl);
                gat_compute(kvA, lo, hi, qraw,
                            c1_0, c1_1, c1_2, c1_3, c2_0, c2_1, c2_2, c2_3,
                            slot, sl, bprm_x32, wv * NPW + ni, tile);
            }
        }
    }
    __syncthreads();

    // coalesced write-out: 64 rows x 16 cols, one float4 per thread
    int n0 = blockIdx.x * NPB;
    int lr = threadIdx.x >> 2;
    int c4 = threadIdx.x & 3;
    int nc = n0 + c4 * 4;
    float4 v = make_float4(tile[lr][c4 * 4 + 0], tile[lr][c4 * 4 + 1],
                           tile[lr][c4 * 4 + 2], tile[lr][c4 * 4 + 3]);
    if (nc + 3 < N) {
        *(float4*)(out + (size_t)lr * N + nc) = v;
    } else {
#pragma unroll
        for (int e = 0; e < 4; e++)
            if (nc + e < N) out[(size_t)lr * N + nc + e] = (&v.x)[e];
    }
}

extern "C" void kernel_launch(void* const* d_in, const int* in_sizes, int n_in,
                              void* d_out, int out_size, void* d_ws, size_t ws_size,
                              hipStream_t stream) {
    const int*   adj = (const int*)  d_in[0];
    const float* Q   = (const float*)d_in[1];
    const float* qw  = (const float*)d_in[2];
    const float* kw  = (const float*)d_in[3];
    const float* aw  = (const float*)d_in[4];
    float*       out = (float*)d_out;

    int N = in_sizes[0] / DEG;  // 50000

    unsigned short* Pqb = (unsigned short*)d_ws;         // [N][64] bf16
    unsigned short* Pkb = Pqb + (size_t)N * NHO;         // [N][64] bf16

    proj_mfma_kernel<<<(N + 63) / 64, 256, 0, stream>>>(Q, qw, kw, Pqb, Pkb, N);

    gat_kernel<<<(N + NPB - 1) / NPB, 256, 0, stream>>>(adj, Pqb, Pkb, aw, out, N);
}